// Round 1
// baseline (940.871 us; speedup 1.0000x reference)
//
#include <hip/hip_runtime.h>
#include <cstdint>
#include <cstddef>

// Problem constants (fixed by the reference)
#define T_DIM 512
#define H_DIM 4096
#define I_DIM 11008
// blocksize BS = 128 (== BN of gemm1, so scale is tile-uniform)

typedef __bf16 bf16_t;
typedef bf16_t bf16x8 __attribute__((ext_vector_type(8)));
typedef float f32x4 __attribute__((ext_vector_type(4)));
typedef unsigned short us16;
typedef us16 us16x8 __attribute__((ext_vector_type(8)));
typedef us16 us16x4 __attribute__((ext_vector_type(4)));

// fp32 -> bf16 RTNE (no NaN handling needed; all values finite & bounded)
__device__ __forceinline__ us16 f2bf(float f) {
    union { float f; uint32_t u; } v; v.f = f;
    uint32_t u = v.u;
    return (us16)((u + 0x7FFFu + ((u >> 16) & 1u)) >> 16);
}

__device__ __forceinline__ f32x4 mfma16(us16x8 a, us16x8 b, f32x4 c) {
    return __builtin_amdgcn_mfma_f32_16x16x32_bf16(
        __builtin_bit_cast(bf16x8, a), __builtin_bit_cast(bf16x8, b), c, 0, 0, 0);
}

// ---------------------------------------------------------------- cvt_x
// x fp32 [T][H] -> bf16 in ws. 8 elems/thread.
__global__ void cvt_x_kernel(const float* __restrict__ x, us16* __restrict__ xb) {
    int idx = (blockIdx.x * 256 + threadIdx.x) * 8;
    float4 a = *(const float4*)(x + idx);
    float4 b = *(const float4*)(x + idx + 4);
    us16x8 v;
    v[0] = f2bf(a.x); v[1] = f2bf(a.y); v[2] = f2bf(a.z); v[3] = f2bf(a.w);
    v[4] = f2bf(b.x); v[5] = f2bf(b.y); v[6] = f2bf(b.z); v[7] = f2bf(b.w);
    *(us16x8*)(xb + idx) = v;
}

// ---------------------------------------------------------------- gemm1 (fused gate+up)
// C[t][i] tiles 128x128, BK=32. A = xb [T][H] bf16 (K-contig). B = Wg/Wu [I][H]
// fp32 (K-contig, NT layout). Dequant scale is ONE scalar per (tile,k-tile)
// because BN == BS == 128 and k-tile stays within one 128-block of H.
// Epilogue: h = silu(g)*u -> bf16 [T][I].
__global__ __launch_bounds__(256, 2) void gemm1_fused(
    const us16*  __restrict__ xb,
    const float* __restrict__ wg,
    const float* __restrict__ wu,
    const float* __restrict__ sgArr,   // [I/128][H/128]
    const float* __restrict__ suArr,
    us16*        __restrict__ hbuf)    // [T][I] bf16
{
    // stride 40 (=80B): 16B-aligned, breaks power-of-2 bank stride
    __shared__ us16 As [128 * 40];
    __shared__ us16 Bgs[128 * 40];
    __shared__ us16 Bus[128 * 40];

    const int t   = threadIdx.x;
    const int bid = blockIdx.x;        // 344 blocks
    const int bm  = bid & 3;           // m fastest: 4 m-tiles of one bn run together -> B re-reads hit L2/LLC
    const int bn  = bid >> 2;
    const int m0  = bm * 128, n0 = bn * 128;

    const int w = t >> 6, l = t & 63;
    const int q = l >> 4, r = l & 15;
    const int m_off = (w >> 1) * 64, n_off = (w & 1) * 64;

    f32x4 accg[4][4], accu[4][4];
    #pragma unroll
    for (int m = 0; m < 4; ++m)
        #pragma unroll
        for (int n = 0; n < 4; ++n) {
            accg[m][n] = f32x4{0.f, 0.f, 0.f, 0.f};
            accu[m][n] = f32x4{0.f, 0.f, 0.f, 0.f};
        }

    for (int kt = 0; kt < H_DIM / 32; ++kt) {
        const int k0 = kt * 32;
        const float sg = sgArr[bn * (H_DIM / 128) + (k0 >> 7)];
        const float su = suArr[bn * (H_DIM / 128) + (k0 >> 7)];

        // stage A: 128x32 bf16, 512 16B-chunks, 2/thread
        #pragma unroll
        for (int p = 0; p < 2; ++p) {
            int c = t + 256 * p;
            int row = c >> 2, col = (c & 3) * 8;
            us16x8 v = *(const us16x8*)(xb + (size_t)(m0 + row) * H_DIM + k0 + col);
            *(us16x8*)(As + row * 40 + col) = v;
        }
        // stage Bg/Bu: 128x32 fp32 each, dequant + cvt, 4 float4-chunks/thread
        #pragma unroll
        for (int p = 0; p < 4; ++p) {
            int c = t + 256 * p;
            int row = c >> 3, col = (c & 7) * 4;
            const size_t gofs = (size_t)(n0 + row) * H_DIM + k0 + col;
            float4 g = *(const float4*)(wg + gofs);
            float4 u = *(const float4*)(wu + gofs);
            us16x4 vg, vu;
            vg[0] = f2bf(g.x * sg); vg[1] = f2bf(g.y * sg);
            vg[2] = f2bf(g.z * sg); vg[3] = f2bf(g.w * sg);
            vu[0] = f2bf(u.x * su); vu[1] = f2bf(u.y * su);
            vu[2] = f2bf(u.z * su); vu[3] = f2bf(u.w * su);
            *(us16x4*)(Bgs + row * 40 + col) = vg;
            *(us16x4*)(Bus + row * 40 + col) = vu;
        }
        __syncthreads();

        us16x8 af[4], bg[4], bu[4];
        #pragma unroll
        for (int m = 0; m < 4; ++m)
            af[m] = *(const us16x8*)(As + (m_off + m * 16 + r) * 40 + q * 8);
        #pragma unroll
        for (int n = 0; n < 4; ++n) {
            bg[n] = *(const us16x8*)(Bgs + (n_off + n * 16 + r) * 40 + q * 8);
            bu[n] = *(const us16x8*)(Bus + (n_off + n * 16 + r) * 40 + q * 8);
        }
        #pragma unroll
        for (int m = 0; m < 4; ++m)
            #pragma unroll
            for (int n = 0; n < 4; ++n) {
                accg[m][n] = mfma16(af[m], bg[n], accg[m][n]);
                accu[m][n] = mfma16(af[m], bu[n], accu[m][n]);
            }
        __syncthreads();
    }

    // epilogue: h = silu(g)*u, bf16 store. C layout: col=lane&15, row=quad*4+reg
    #pragma unroll
    for (int m = 0; m < 4; ++m)
        #pragma unroll
        for (int n = 0; n < 4; ++n)
            #pragma unroll
            for (int rr = 0; rr < 4; ++rr) {
                int grow = m0 + m_off + m * 16 + q * 4 + rr;
                int gcol = n0 + n_off + n * 16 + r;
                float g = accg[m][n][rr];
                float u = accu[m][n][rr];
                float hv = (g / (1.0f + __expf(-g))) * u;
                hbuf[(size_t)grow * I_DIM + gcol] = f2bf(hv);
            }
}

// ---------------------------------------------------------------- gemm2
// out[t][h] = h[T][I] @ Wd[I][H]. BM=128, BN=64, BK=32. Wd is N-contiguous
// (NN layout) -> staged TRANSPOSED into LDS layout [kb=k/8][n][k%8] so
// b-fragments are one ds_read_b128. Scale again tile-uniform.
__global__ __launch_bounds__(256, 2) void gemm2(
    const us16*  __restrict__ hbuf,    // [T][I] bf16
    const float* __restrict__ wd,      // [I][H] fp32
    const float* __restrict__ sdArr,   // [I/128][H/128]
    float*       __restrict__ out)     // [T][H] fp32
{
    __shared__ us16 As[128 * 40];
    __shared__ us16 Bs[4 * 64 * 8];    // [kb][n][j]

    const int t   = threadIdx.x;
    const int bid = blockIdx.x;        // 256 blocks
    const int bm  = bid & 3;
    const int bn  = bid >> 2;          // 0..63
    const int m0  = bm * 128, n0 = bn * 64;

    const int w = t >> 6, l = t & 63;
    const int q = l >> 4, r = l & 15;
    const int m_off = (w >> 1) * 64, n_off = (w & 1) * 32;

    f32x4 acc[4][2];
    #pragma unroll
    for (int m = 0; m < 4; ++m)
        #pragma unroll
        for (int n = 0; n < 2; ++n) acc[m][n] = f32x4{0.f, 0.f, 0.f, 0.f};

    const int sn  = t & 63;   // staging: n position
    const int skb = t >> 6;   // staging: which 8-row k group
    const int nblk = n0 >> 7; // scale column block

    for (int kt = 0; kt < I_DIM / 32; ++kt) {
        const int k0 = kt * 32;
        const float sd = sdArr[(k0 >> 7) * (H_DIM / 128) + nblk];

        // stage A: 128x32 bf16 from hbuf
        #pragma unroll
        for (int p = 0; p < 2; ++p) {
            int c = t + 256 * p;
            int row = c >> 2, col = (c & 3) * 8;
            us16x8 v = *(const us16x8*)(hbuf + (size_t)(m0 + row) * I_DIM + k0 + col);
            *(us16x8*)(As + row * 40 + col) = v;
        }
        // stage B transposed: thread gathers 8 k-strided dwords (coalesced
        // across lanes: consecutive lanes -> consecutive n), one ds_write_b128
        {
            const float* src = wd + (size_t)(k0 + skb * 8) * H_DIM + n0 + sn;
            us16x8 v;
            #pragma unroll
            for (int rr = 0; rr < 8; ++rr)
                v[rr] = f2bf(src[(size_t)rr * H_DIM] * sd);
            *(us16x8*)(Bs + (skb * 64 + sn) * 8) = v;
        }
        __syncthreads();

        us16x8 af[4], bfr[2];
        #pragma unroll
        for (int m = 0; m < 4; ++m)
            af[m] = *(const us16x8*)(As + (m_off + m * 16 + r) * 40 + q * 8);
        #pragma unroll
        for (int n = 0; n < 2; ++n)
            bfr[n] = *(const us16x8*)(Bs + (q * 64 + n_off + n * 16 + r) * 8);
        #pragma unroll
        for (int m = 0; m < 4; ++m)
            #pragma unroll
            for (int n = 0; n < 2; ++n)
                acc[m][n] = mfma16(af[m], bfr[n], acc[m][n]);
        __syncthreads();
    }

    #pragma unroll
    for (int m = 0; m < 4; ++m)
        #pragma unroll
        for (int n = 0; n < 2; ++n)
            #pragma unroll
            for (int rr = 0; rr < 4; ++rr) {
                int grow = m0 + m_off + m * 16 + q * 4 + rr;
                int gcol = n0 + n_off + n * 16 + r;
                out[(size_t)grow * H_DIM + gcol] = acc[m][n][rr];
            }
}

// ---------------------------------------------------------------- launch
extern "C" void kernel_launch(void* const* d_in, const int* in_sizes, int n_in,
                              void* d_out, int out_size, void* d_ws, size_t ws_size,
                              hipStream_t stream) {
    const float* x  = (const float*)d_in[0];
    const float* wg = (const float*)d_in[1];
    const float* wu = (const float*)d_in[2];
    const float* wd = (const float*)d_in[3];
    const float* sg = (const float*)d_in[4];
    const float* su = (const float*)d_in[5];
    const float* sd = (const float*)d_in[6];
    // d_in[7] = blocksize (=128), baked into the kernels
    float* out = (float*)d_out;

    us16* xb = (us16*)d_ws;                                        // 4 MB
    us16* hb = (us16*)((char*)d_ws + (size_t)T_DIM * H_DIM * 2);   // 11.3 MB

    cvt_x_kernel<<<(T_DIM * H_DIM) / (256 * 8), 256, 0, stream>>>(x, xb);
    gemm1_fused<<<(I_DIM / 128) * (T_DIM / 128), 256, 0, stream>>>(xb, wg, wu, sg, su, hb);
    gemm2<<<(H_DIM / 64) * (T_DIM / 128), 256, 0, stream>>>(hb, wd, sd, out);
}

// Round 3
// 811.986 us; speedup vs baseline: 1.1587x; 1.1587x over previous
//
#include <hip/hip_runtime.h>
#include <cstdint>
#include <cstddef>

// Problem constants (fixed by the reference)
#define T_DIM 512
#define H_DIM 4096
#define I_DIM 11008
#define KSPLIT 4
// blocksize BS = 128

typedef __bf16 bf16_t;
typedef bf16_t bf16x8 __attribute__((ext_vector_type(8)));
typedef float f32x4 __attribute__((ext_vector_type(4)));
typedef unsigned short us16;
typedef us16 us16x8 __attribute__((ext_vector_type(8)));
typedef us16 us16x4 __attribute__((ext_vector_type(4)));

// fp32 -> bf16 RTNE
__device__ __forceinline__ us16 f2bf(float f) {
    union { float f; uint32_t u; } v; v.f = f;
    uint32_t u = v.u;
    return (us16)((u + 0x7FFFu + ((u >> 16) & 1u)) >> 16);
}

// pack two fp32 -> bf16x2 in one dword (RTNE per element)
__device__ __forceinline__ uint32_t pkbf(float a, float b) {
    return (uint32_t)f2bf(a) | ((uint32_t)f2bf(b) << 16);
}

__device__ __forceinline__ f32x4 mfma16(us16x8 a, us16x8 b, f32x4 c) {
    return __builtin_amdgcn_mfma_f32_16x16x32_bf16(
        __builtin_bit_cast(bf16x8, a), __builtin_bit_cast(bf16x8, b), c, 0, 0, 0);
}

// async global->LDS, 16B per lane. lds dest = wave-uniform base + lane*16B.
__device__ __forceinline__ void gload_lds16(const us16* g, us16* l) {
    __builtin_amdgcn_global_load_lds(
        (const __attribute__((address_space(1))) void*)g,
        (__attribute__((address_space(3))) void*)l, 16, 0, 0);
}

// ---------------------------------------------------------------- cvt_x
__global__ void cvt_x_kernel(const float* __restrict__ x, us16* __restrict__ xb) {
    int idx = (blockIdx.x * 256 + threadIdx.x) * 8;
    float4 a = *(const float4*)(x + idx);
    float4 b = *(const float4*)(x + idx + 4);
    us16x8 v;
    v[0] = f2bf(a.x); v[1] = f2bf(a.y); v[2] = f2bf(a.z); v[3] = f2bf(a.w);
    v[4] = f2bf(b.x); v[5] = f2bf(b.y); v[6] = f2bf(b.z); v[7] = f2bf(b.w);
    *(us16x8*)(xb + idx) = v;
}

// ---------------------------------------------------------------- trans_wd
// Wd [I][H] fp32 -> Wdt [H][I] bf16 dequantized. 64x64 LDS-transpose tiles,
// both global sides coalesced. Scale block-uniform (64-tile within 128-block).
__global__ __launch_bounds__(256) void trans_wd(
    const float* __restrict__ wd, const float* __restrict__ sd, us16* __restrict__ wdt)
{
    __shared__ us16 tile[64 * 68];   // stride 68: 8B-aligned rows, breaks pow2 banks
    const int t   = threadIdx.x;
    const int bid = blockIdx.x;
    const int bi  = bid % (I_DIM / 64);
    const int bh  = bid / (I_DIM / 64);
    const int i0  = bi * 64, h0 = bh * 64;
    const float s = sd[(i0 >> 7) * (H_DIM / 128) + (h0 >> 7)];
    #pragma unroll
    for (int p = 0; p < 4; ++p) {
        int c = t + 256 * p;
        int i = c >> 4, h4 = (c & 15) * 4;
        float4 v = *(const float4*)(wd + (size_t)(i0 + i) * H_DIM + h0 + h4);
        us16x4 o;
        o[0] = f2bf(v.x * s); o[1] = f2bf(v.y * s);
        o[2] = f2bf(v.z * s); o[3] = f2bf(v.w * s);
        *(us16x4*)(tile + i * 68 + h4) = o;
    }
    __syncthreads();
    #pragma unroll
    for (int p = 0; p < 4; ++p) {
        int c = t + 256 * p;
        int h = c >> 4, i4 = (c & 15) * 4;
        us16x4 o;
        #pragma unroll
        for (int j = 0; j < 4; ++j) o[j] = tile[(i4 + j) * 68 + h];
        *(us16x4*)(wdt + (size_t)(h0 + h) * I_DIM + i0 + i4) = o;
    }
}

// ---------------------------------------------------------------- gemm1 (fused gate+up)
// 128x128x32 tiles. A staged via global_load_lds (bf16). B dequant fused:
// fp32 loads -> cvt -> LDS. Epilogue silu(g)*u -> bf16 hbuf.
__global__ __launch_bounds__(256, 2) void gemm1_fused(
    const us16*  __restrict__ xb,
    const float* __restrict__ wg,
    const float* __restrict__ wu,
    const float* __restrict__ sgArr,
    const float* __restrict__ suArr,
    us16*        __restrict__ hbuf)
{
    __shared__ us16 As [128 * 32];     // unpadded: global_load_lds layout
    __shared__ us16 Bgs[128 * 40];
    __shared__ us16 Bus[128 * 40];

    const int t   = threadIdx.x;
    const int bid = blockIdx.x;        // 344
    const int bm  = bid & 3;
    const int bn  = bid >> 2;
    const int m0  = bm * 128, n0 = bn * 128;

    const int w = t >> 6, l = t & 63;
    const int q = l >> 4, r = l & 15;
    const int m_off = (w >> 1) * 64, n_off = (w & 1) * 64;

    const int arow = w * 16 + (l >> 2);     // row within 64-row group
    const int acol = (l & 3) * 8;

    f32x4 accg[4][4], accu[4][4];
    #pragma unroll
    for (int m = 0; m < 4; ++m)
        #pragma unroll
        for (int n = 0; n < 4; ++n) {
            accg[m][n] = f32x4{0.f, 0.f, 0.f, 0.f};
            accu[m][n] = f32x4{0.f, 0.f, 0.f, 0.f};
        }

    for (int kt = 0; kt < H_DIM / 32; ++kt) {
        const int k0 = kt * 32;
        const float sg = sgArr[bn * (H_DIM / 128) + (k0 >> 7)];
        const float su = suArr[bn * (H_DIM / 128) + (k0 >> 7)];

        // A: 2 async 16B/lane drops per thread (wave covers 16 rows/call)
        #pragma unroll
        for (int p = 0; p < 2; ++p) {
            gload_lds16(xb + (size_t)(m0 + p * 64 + arow) * H_DIM + k0 + acol,
                        As + (p * 64 + w * 16) * 32);
        }
        // B: fp32 load + dequant + cvt
        #pragma unroll
        for (int p = 0; p < 4; ++p) {
            int c = t + 256 * p;
            int row = c >> 3, col = (c & 7) * 4;
            const size_t gofs = (size_t)(n0 + row) * H_DIM + k0 + col;
            float4 g = *(const float4*)(wg + gofs);
            float4 u = *(const float4*)(wu + gofs);
            uint2 vg, vu;
            vg.x = pkbf(g.x * sg, g.y * sg); vg.y = pkbf(g.z * sg, g.w * sg);
            vu.x = pkbf(u.x * su, u.y * su); vu.y = pkbf(u.z * su, u.w * su);
            *(uint2*)(Bgs + row * 40 + col) = vg;
            *(uint2*)(Bus + row * 40 + col) = vu;
        }
        __syncthreads();

        us16x8 af[4], bg[4], bu[4];
        #pragma unroll
        for (int m = 0; m < 4; ++m)
            af[m] = *(const us16x8*)(As + (m_off + m * 16 + r) * 32 + q * 8);
        #pragma unroll
        for (int n = 0; n < 4; ++n) {
            bg[n] = *(const us16x8*)(Bgs + (n_off + n * 16 + r) * 40 + q * 8);
            bu[n] = *(const us16x8*)(Bus + (n_off + n * 16 + r) * 40 + q * 8);
        }
        #pragma unroll
        for (int m = 0; m < 4; ++m)
            #pragma unroll
            for (int n = 0; n < 4; ++n) {
                accg[m][n] = mfma16(af[m], bg[n], accg[m][n]);
                accu[m][n] = mfma16(af[m], bu[n], accu[m][n]);
            }
        __syncthreads();
    }

    #pragma unroll
    for (int m = 0; m < 4; ++m)
        #pragma unroll
        for (int n = 0; n < 4; ++n)
            #pragma unroll
            for (int rr = 0; rr < 4; ++rr) {
                int grow = m0 + m_off + m * 16 + q * 4 + rr;
                int gcol = n0 + n_off + n * 16 + r;
                float g = accg[m][n][rr];
                float u = accu[m][n][rr];
                float hv = (g / (1.0f + __expf(-g))) * u;
                hbuf[(size_t)grow * I_DIM + gcol] = f2bf(hv);
            }
}

// ---------------------------------------------------------------- gemm2 split-K
// out[t][h] += h[T][I] @ Wdt^T (both bf16, K-contig). 128x128 tile, split-K x4,
// global_load_lds both operands, fp32 atomicAdd epilogue (out pre-zeroed).
__global__ __launch_bounds__(256, 2) void gemm2_splitk(
    const us16* __restrict__ hbuf,   // [T][I]
    const us16* __restrict__ wdt,    // [H][I]
    float*      __restrict__ out)    // [T][H]
{
    __shared__ us16 As[128 * 32];
    __shared__ us16 Bs[128 * 32];

    const int t   = threadIdx.x;
    const int bid = blockIdx.x;          // 512
    const int bm  = bid & 3;
    const int bn  = (bid >> 2) & 31;
    const int bk  = bid >> 7;
    const int m0  = bm * 128, n0 = bn * 128;
    const int kbase = bk * (I_DIM / KSPLIT);

    const int w = t >> 6, l = t & 63;
    const int q = l >> 4, r = l & 15;
    const int m_off = (w >> 1) * 64, n_off = (w & 1) * 64;

    const int arow = w * 16 + (l >> 2);
    const int acol = (l & 3) * 8;

    f32x4 acc[4][4];
    #pragma unroll
    for (int m = 0; m < 4; ++m)
        #pragma unroll
        for (int n = 0; n < 4; ++n) acc[m][n] = f32x4{0.f, 0.f, 0.f, 0.f};

    for (int kt = 0; kt < (I_DIM / KSPLIT) / 32; ++kt) {   // 86
        const int k0 = kbase + kt * 32;
        #pragma unroll
        for (int p = 0; p < 2; ++p) {
            gload_lds16(hbuf + (size_t)(m0 + p * 64 + arow) * I_DIM + k0 + acol,
                        As + (p * 64 + w * 16) * 32);
            gload_lds16(wdt + (size_t)(n0 + p * 64 + arow) * I_DIM + k0 + acol,
                        Bs + (p * 64 + w * 16) * 32);
        }
        __syncthreads();

        us16x8 af[4], bfr[4];
        #pragma unroll
        for (int m = 0; m < 4; ++m)
            af[m] = *(const us16x8*)(As + (m_off + m * 16 + r) * 32 + q * 8);
        #pragma unroll
        for (int n = 0; n < 4; ++n)
            bfr[n] = *(const us16x8*)(Bs + (n_off + n * 16 + r) * 32 + q * 8);
        #pragma unroll
        for (int m = 0; m < 4; ++m)
            #pragma unroll
            for (int n = 0; n < 4; ++n)
                acc[m][n] = mfma16(af[m], bfr[n], acc[m][n]);
        __syncthreads();
    }

    #pragma unroll
    for (int m = 0; m < 4; ++m)
        #pragma unroll
        for (int n = 0; n < 4; ++n)
            #pragma unroll
            for (int rr = 0; rr < 4; ++rr) {
                int grow = m0 + m_off + m * 16 + q * 4 + rr;
                int gcol = n0 + n_off + n * 16 + r;
                atomicAdd(&out[(size_t)grow * H_DIM + gcol], acc[m][n][rr]);
            }
}

// ---------------------------------------------------------------- fallback gemm2 (R1)
// Used only if ws_size can't hold the 90MB transposed-Wd buffer.
__global__ __launch_bounds__(256, 2) void gemm2_fallback(
    const us16*  __restrict__ hbuf,
    const float* __restrict__ wd,
    const float* __restrict__ sdArr,
    float*       __restrict__ out)
{
    __shared__ us16 As[128 * 40];
    __shared__ us16 Bs[4 * 64 * 8];

    const int t   = threadIdx.x;
    const int bid = blockIdx.x;
    const int bm  = bid & 3;
    const int bn  = bid >> 2;
    const int m0  = bm * 128, n0 = bn * 64;

    const int w = t >> 6, l = t & 63;
    const int q = l >> 4, r = l & 15;
    const int m_off = (w >> 1) * 64, n_off = (w & 1) * 32;

    f32x4 acc[4][2];
    #pragma unroll
    for (int m = 0; m < 4; ++m)
        #pragma unroll
        for (int n = 0; n < 2; ++n) acc[m][n] = f32x4{0.f, 0.f, 0.f, 0.f};

    const int sn  = t & 63;
    const int skb = t >> 6;
    const int nblk = n0 >> 7;

    for (int kt = 0; kt < I_DIM / 32; ++kt) {
        const int k0 = kt * 32;
        const float sd = sdArr[(k0 >> 7) * (H_DIM / 128) + nblk];
        #pragma unroll
        for (int p = 0; p < 2; ++p) {
            int c = t + 256 * p;
            int row = c >> 2, col = (c & 3) * 8;
            us16x8 v = *(const us16x8*)(hbuf + (size_t)(m0 + row) * I_DIM + k0 + col);
            *(us16x8*)(As + row * 40 + col) = v;
        }
        {
            const float* src = wd + (size_t)(k0 + skb * 8) * H_DIM + n0 + sn;
            us16x8 v;
            #pragma unroll
            for (int rr = 0; rr < 8; ++rr)
                v[rr] = f2bf(src[(size_t)rr * H_DIM] * sd);
            *(us16x8*)(Bs + (skb * 64 + sn) * 8) = v;
        }
        __syncthreads();

        us16x8 af[4], bfr[2];
        #pragma unroll
        for (int m = 0; m < 4; ++m)
            af[m] = *(const us16x8*)(As + (m_off + m * 16 + r) * 40 + q * 8);
        #pragma unroll
        for (int n = 0; n < 2; ++n)
            bfr[n] = *(const us16x8*)(Bs + (q * 64 + n_off + n * 16 + r) * 8);
        #pragma unroll
        for (int m = 0; m < 4; ++m)
            #pragma unroll
            for (int n = 0; n < 2; ++n)
                acc[m][n] = mfma16(af[m], bfr[n], acc[m][n]);
        __syncthreads();
    }

    #pragma unroll
    for (int m = 0; m < 4; ++m)
        #pragma unroll
        for (int n = 0; n < 2; ++n)
            #pragma unroll
            for (int rr = 0; rr < 4; ++rr) {
                int grow = m0 + m_off + m * 16 + q * 4 + rr;
                int gcol = n0 + n_off + n * 16 + r;
                out[(size_t)grow * H_DIM + gcol] = acc[m][n][rr];
            }
}

// ---------------------------------------------------------------- launch
extern "C" void kernel_launch(void* const* d_in, const int* in_sizes, int n_in,
                              void* d_out, int out_size, void* d_ws, size_t ws_size,
                              hipStream_t stream) {
    const float* x  = (const float*)d_in[0];
    const float* wg = (const float*)d_in[1];
    const float* wu = (const float*)d_in[2];
    const float* wd = (const float*)d_in[3];
    const float* sg = (const float*)d_in[4];
    const float* su = (const float*)d_in[5];
    const float* sd = (const float*)d_in[6];
    float* out = (float*)d_out;

    const size_t xb_bytes  = (size_t)T_DIM * H_DIM * 2;   //  4.0 MB
    const size_t hb_bytes  = (size_t)T_DIM * I_DIM * 2;   // 11.3 MB
    const size_t wdt_bytes = (size_t)H_DIM * I_DIM * 2;   // 90.2 MB

    us16* xb  = (us16*)d_ws;
    us16* hb  = (us16*)((char*)d_ws + xb_bytes);
    us16* wdt = (us16*)((char*)d_ws + xb_bytes + hb_bytes);

    cvt_x_kernel<<<(T_DIM * H_DIM) / (256 * 8), 256, 0, stream>>>(x, xb);
    gemm1_fused<<<(I_DIM / 128) * (T_DIM / 128), 256, 0, stream>>>(xb, wg, wu, sg, su, hb);

    if (ws_size >= xb_bytes + hb_bytes + wdt_bytes) {
        trans_wd<<<(I_DIM / 64) * (H_DIM / 64), 256, 0, stream>>>(wd, sd, wdt);
        (void)hipMemsetAsync(out, 0, (size_t)T_DIM * H_DIM * sizeof(float), stream);
        gemm2_splitk<<<(T_DIM / 128) * (H_DIM / 128) * KSPLIT, 256, 0, stream>>>(hb, wdt, out);
    } else {
        gemm2_fallback<<<(H_DIM / 64) * (T_DIM / 128), 256, 0, stream>>>(hb, wd, sd, out);
    }
}

// Round 4
// 726.548 us; speedup vs baseline: 1.2950x; 1.1176x over previous
//
#include <hip/hip_runtime.h>
#include <hip/hip_bf16.h>
#include <cstdint>
#include <cstddef>

#define T_DIM 512
#define H_DIM 4096
#define I_DIM 11008
#define KSPLIT 4
// blocksize BS = 128

typedef __bf16 bf16_t;
typedef bf16_t bf16x8 __attribute__((ext_vector_type(8)));
typedef float f32x4 __attribute__((ext_vector_type(4)));
typedef unsigned short us16;
typedef us16 us16x8 __attribute__((ext_vector_type(8)));
typedef us16 us16x4 __attribute__((ext_vector_type(4)));

// fp32 -> bf16 RTNE (scalar)
__device__ __forceinline__ us16 f2bf(float f) {
    union { float f; uint32_t u; } v; v.f = f;
    uint32_t u = v.u;
    return (us16)((u + 0x7FFFu + ((u >> 16) & 1u)) >> 16);
}

// packed fp32x2 -> bf16x2 dword via HW v_cvt_pk_bf16_f32 (RTNE)
__device__ __forceinline__ uint32_t pkbf(float a, float b) {
    __hip_bfloat162 h = __float22bfloat162_rn(make_float2(a, b));
    uint32_t u;
    __builtin_memcpy(&u, &h, 4);
    return u;
}

__device__ __forceinline__ f32x4 mfma16(us16x8 a, us16x8 b, f32x4 c) {
    return __builtin_amdgcn_mfma_f32_16x16x32_bf16(
        __builtin_bit_cast(bf16x8, a), __builtin_bit_cast(bf16x8, b), c, 0, 0, 0);
}

// async global->LDS, 16B per lane (used by gemm2 only)
__device__ __forceinline__ void gload_lds16(const us16* g, us16* l) {
    __builtin_amdgcn_global_load_lds(
        (const __attribute__((address_space(1))) void*)g,
        (__attribute__((address_space(3))) void*)l, 16, 0, 0);
}

// ---------------------------------------------------------------- cvt_x
__global__ void cvt_x_kernel(const float* __restrict__ x, us16* __restrict__ xb) {
    int idx = (blockIdx.x * 256 + threadIdx.x) * 8;
    float4 a = *(const float4*)(x + idx);
    float4 b = *(const float4*)(x + idx + 4);
    us16x8 v;
    v[0] = f2bf(a.x); v[1] = f2bf(a.y); v[2] = f2bf(a.z); v[3] = f2bf(a.w);
    v[4] = f2bf(b.x); v[5] = f2bf(b.y); v[6] = f2bf(b.z); v[7] = f2bf(b.w);
    *(us16x8*)(xb + idx) = v;
}

// ---------------------------------------------------------------- trans_wd (no LDS)
// Wd [I][H] fp32 -> Wdt [H][I] bf16 dequant. Thread owns one i-row's 64B
// h-chunk (4x dwordx4, full line utilization); writes 16 lane-coalesced 2B
// stores (128B/wave-instr). Grid 43 x 256 = 11008 blocks.
__global__ __launch_bounds__(256) void trans_wd(
    const float* __restrict__ wd, const float* __restrict__ sd, us16* __restrict__ wdt)
{
    const int t   = threadIdx.x;
    const int bid = blockIdx.x;
    const int bi  = bid % (I_DIM / 256);      // 43
    const int bh  = bid / (I_DIM / 256);      // 256
    const int i   = bi * 256 + t;
    const int h0  = bh * 16;
    const float s = sd[(i >> 7) * (H_DIM / 128) + (h0 >> 7)];
    const float* src = wd + (size_t)i * H_DIM + h0;
    float4 v0 = *(const float4*)(src + 0);
    float4 v1 = *(const float4*)(src + 4);
    float4 v2 = *(const float4*)(src + 8);
    float4 v3 = *(const float4*)(src + 12);
    us16 o[16];
    o[0]=f2bf(v0.x*s); o[1]=f2bf(v0.y*s); o[2]=f2bf(v0.z*s); o[3]=f2bf(v0.w*s);
    o[4]=f2bf(v1.x*s); o[5]=f2bf(v1.y*s); o[6]=f2bf(v1.z*s); o[7]=f2bf(v1.w*s);
    o[8]=f2bf(v2.x*s); o[9]=f2bf(v2.y*s); o[10]=f2bf(v2.z*s); o[11]=f2bf(v2.w*s);
    o[12]=f2bf(v3.x*s); o[13]=f2bf(v3.y*s); o[14]=f2bf(v3.z*s); o[15]=f2bf(v3.w*s);
    #pragma unroll
    for (int j = 0; j < 16; ++j)
        wdt[(size_t)(h0 + j) * I_DIM + i] = o[j];
}

// ---------------------------------------------------------------- gemm1 (fused gate+up)
// BM=128 BN=64 BK=64, grid 4m x 172n = 688 blocks, 3 blocks/CU.
// Register-prefetched staging (A bf16 + B fp32->bf16 dequant); pre-MFMA
// barrier is raw lgkmcnt(0)+s_barrier so next-iter loads stay in flight.
__global__ __launch_bounds__(256, 3) void gemm1_fused(
    const us16*  __restrict__ xb,
    const float* __restrict__ wg,
    const float* __restrict__ wu,
    const float* __restrict__ sgArr,
    const float* __restrict__ suArr,
    us16*        __restrict__ hbuf)
{
    __shared__ us16 As [128 * 72];    // stride 72: 16B-aligned, conflict-free frag reads
    __shared__ us16 Bgs[64 * 72];
    __shared__ us16 Bus[64 * 72];

    const int t   = threadIdx.x;
    const int bid = blockIdx.x;       // 688
    const int bm  = bid & 3;
    const int bn  = bid >> 2;         // 0..171
    const int m0  = bm * 128, n0 = bn * 64;

    const int w = t >> 6, l = t & 63;
    const int q = l >> 4, r = l & 15;
    const int m_off = (w >> 1) * 64, n_off = (w & 1) * 32;

    // staging coordinates (fixed per thread)
    const int ar[4] = { t >> 3, (t + 256) >> 3, (t + 512) >> 3, (t + 768) >> 3 };
    const int ac    = (t & 7) * 8;                 // A: col in elems
    const int br[4] = { t >> 4, (t + 256) >> 4, (t + 512) >> 4, (t + 768) >> 4 };
    const int bc    = (t & 15) * 4;                // B: col in floats

    f32x4 accg[4][2], accu[4][2];
    #pragma unroll
    for (int m = 0; m < 4; ++m)
        #pragma unroll
        for (int n = 0; n < 2; ++n) {
            accg[m][n] = f32x4{0.f,0.f,0.f,0.f};
            accu[m][n] = f32x4{0.f,0.f,0.f,0.f};
        }

    us16x8 ab[4];
    float4 gb[4], ub[4];

    // prologue: prefetch iter 0
    {
        const int k0 = 0;
        #pragma unroll
        for (int p = 0; p < 4; ++p)
            ab[p] = *(const us16x8*)(xb + (size_t)(m0 + ar[p]) * H_DIM + k0 + ac);
        #pragma unroll
        for (int p = 0; p < 4; ++p) {
            gb[p] = *(const float4*)(wg + (size_t)(n0 + br[p]) * H_DIM + k0 + bc);
            ub[p] = *(const float4*)(wu + (size_t)(n0 + br[p]) * H_DIM + k0 + bc);
        }
    }

    for (int kt = 0; kt < H_DIM / 64; ++kt) {      // 64 iters
        const float sg = sgArr[(bn >> 1) * (H_DIM / 128) + (kt >> 1)];
        const float su = suArr[(bn >> 1) * (H_DIM / 128) + (kt >> 1)];

        __builtin_amdgcn_s_barrier();              // LDS WAR (reads of kt-1 done)

        // consume prefetched regs -> LDS
        #pragma unroll
        for (int p = 0; p < 4; ++p)
            *(us16x8*)(As + ar[p] * 72 + ac) = ab[p];
        #pragma unroll
        for (int p = 0; p < 4; ++p) {
            uint2 vg, vu;
            vg.x = pkbf(gb[p].x * sg, gb[p].y * sg);
            vg.y = pkbf(gb[p].z * sg, gb[p].w * sg);
            vu.x = pkbf(ub[p].x * su, ub[p].y * su);
            vu.y = pkbf(ub[p].z * su, ub[p].w * su);
            *(uint2*)(Bgs + br[p] * 72 + bc) = vg;
            *(uint2*)(Bus + br[p] * 72 + bc) = vu;
        }

        // prefetch next iter (wrap: last prefetch redundant but keeps counts uniform)
        {
            const int kn = ((kt + 1) & 63) * 64;
            #pragma unroll
            for (int p = 0; p < 4; ++p)
                ab[p] = *(const us16x8*)(xb + (size_t)(m0 + ar[p]) * H_DIM + kn + ac);
            #pragma unroll
            for (int p = 0; p < 4; ++p) {
                gb[p] = *(const float4*)(wg + (size_t)(n0 + br[p]) * H_DIM + kn + bc);
                ub[p] = *(const float4*)(wu + (size_t)(n0 + br[p]) * H_DIM + kn + bc);
            }
        }

        // pre-MFMA barrier WITHOUT vmcnt drain: prefetch stays in flight
        __builtin_amdgcn_s_waitcnt(0xC07F);        // lgkmcnt(0) only
        __builtin_amdgcn_s_barrier();

        #pragma unroll
        for (int ks = 0; ks < 2; ++ks) {
            us16x8 af[4], bg[2], bu[2];
            #pragma unroll
            for (int m = 0; m < 4; ++m)
                af[m] = *(const us16x8*)(As + (m_off + m * 16 + r) * 72 + ks * 32 + q * 8);
            #pragma unroll
            for (int n = 0; n < 2; ++n) {
                bg[n] = *(const us16x8*)(Bgs + (n_off + n * 16 + r) * 72 + ks * 32 + q * 8);
                bu[n] = *(const us16x8*)(Bus + (n_off + n * 16 + r) * 72 + ks * 32 + q * 8);
            }
            #pragma unroll
            for (int m = 0; m < 4; ++m)
                #pragma unroll
                for (int n = 0; n < 2; ++n) {
                    accg[m][n] = mfma16(af[m], bg[n], accg[m][n]);
                    accu[m][n] = mfma16(af[m], bu[n], accu[m][n]);
                }
        }
    }

    #pragma unroll
    for (int m = 0; m < 4; ++m)
        #pragma unroll
        for (int n = 0; n < 2; ++n)
            #pragma unroll
            for (int rr = 0; rr < 4; ++rr) {
                int grow = m0 + m_off + m * 16 + q * 4 + rr;
                int gcol = n0 + n_off + n * 16 + r;
                float g = accg[m][n][rr];
                float u = accu[m][n][rr];
                float hv = (g / (1.0f + __expf(-g))) * u;
                hbuf[(size_t)grow * I_DIM + gcol] = f2bf(hv);
            }
}

// ---------------------------------------------------------------- gemm2 split-K
// 128x128 tile, KSPLIT=4 -> 512 blocks = 2/CU. Both operands bf16 K-contig
// via global_load_lds. Epilogue: plain store to partials (or atomicAdd).
template <bool USE_PART>
__global__ __launch_bounds__(256, 2) void gemm2_splitk(
    const us16* __restrict__ hbuf,   // [T][I]
    const us16* __restrict__ wdt,    // [H][I]
    float*      __restrict__ outp)   // partials [KSPLIT][T][H] or out [T][H]
{
    __shared__ us16 As[128 * 32];
    __shared__ us16 Bs[128 * 32];

    const int t   = threadIdx.x;
    const int bid = blockIdx.x;          // 512
    const int bm  = bid & 3;
    const int bn  = (bid >> 2) & 31;
    const int bk  = bid >> 7;
    const int m0  = bm * 128, n0 = bn * 128;
    const int kbase = bk * (I_DIM / KSPLIT);

    const int w = t >> 6, l = t & 63;
    const int q = l >> 4, r = l & 15;
    const int m_off = (w >> 1) * 64, n_off = (w & 1) * 64;

    const int arow = w * 16 + (l >> 2);
    const int acol = (l & 3) * 8;

    f32x4 acc[4][4];
    #pragma unroll
    for (int m = 0; m < 4; ++m)
        #pragma unroll
        for (int n = 0; n < 4; ++n) acc[m][n] = f32x4{0.f,0.f,0.f,0.f};

    for (int kt = 0; kt < (I_DIM / KSPLIT) / 32; ++kt) {   // 86
        const int k0 = kbase + kt * 32;
        #pragma unroll
        for (int p = 0; p < 2; ++p) {
            gload_lds16(hbuf + (size_t)(m0 + p * 64 + arow) * I_DIM + k0 + acol,
                        As + (p * 64 + w * 16) * 32);
            gload_lds16(wdt + (size_t)(n0 + p * 64 + arow) * I_DIM + k0 + acol,
                        Bs + (p * 64 + w * 16) * 32);
        }
        __syncthreads();

        us16x8 af[4], bfr[4];
        #pragma unroll
        for (int m = 0; m < 4; ++m)
            af[m] = *(const us16x8*)(As + (m_off + m * 16 + r) * 32 + q * 8);
        #pragma unroll
        for (int n = 0; n < 4; ++n)
            bfr[n] = *(const us16x8*)(Bs + (n_off + n * 16 + r) * 32 + q * 8);
        #pragma unroll
        for (int m = 0; m < 4; ++m)
            #pragma unroll
            for (int n = 0; n < 4; ++n)
                acc[m][n] = mfma16(af[m], bfr[n], acc[m][n]);
        __syncthreads();
    }

    float* base = USE_PART ? outp + (size_t)bk * T_DIM * H_DIM : outp;
    #pragma unroll
    for (int m = 0; m < 4; ++m)
        #pragma unroll
        for (int n = 0; n < 4; ++n)
            #pragma unroll
            for (int rr = 0; rr < 4; ++rr) {
                int grow = m0 + m_off + m * 16 + q * 4 + rr;
                int gcol = n0 + n_off + n * 16 + r;
                if (USE_PART)
                    base[(size_t)grow * H_DIM + gcol] = acc[m][n][rr];
                else
                    atomicAdd(&base[(size_t)grow * H_DIM + gcol], acc[m][n][rr]);
            }
}

// ---------------------------------------------------------------- reduce partials
__global__ void reduce4_kernel(const float* __restrict__ part, float* __restrict__ out) {
    const size_t i = ((size_t)blockIdx.x * 256 + threadIdx.x) * 4;
    const size_t S = (size_t)T_DIM * H_DIM;
    float4 a = *(const float4*)(part + i);
    float4 b = *(const float4*)(part + S + i);
    float4 c = *(const float4*)(part + 2 * S + i);
    float4 d = *(const float4*)(part + 3 * S + i);
    float4 o;
    o.x = a.x + b.x + c.x + d.x;
    o.y = a.y + b.y + c.y + d.y;
    o.z = a.z + b.z + c.z + d.z;
    o.w = a.w + b.w + c.w + d.w;
    *(float4*)(out + i) = o;
}

// ---------------------------------------------------------------- launch
extern "C" void kernel_launch(void* const* d_in, const int* in_sizes, int n_in,
                              void* d_out, int out_size, void* d_ws, size_t ws_size,
                              hipStream_t stream) {
    const float* x  = (const float*)d_in[0];
    const float* wg = (const float*)d_in[1];
    const float* wu = (const float*)d_in[2];
    const float* wd = (const float*)d_in[3];
    const float* sg = (const float*)d_in[4];
    const float* su = (const float*)d_in[5];
    const float* sd = (const float*)d_in[6];
    float* out = (float*)d_out;

    const size_t xb_bytes   = (size_t)T_DIM * H_DIM * 2;           //  4.0 MB
    const size_t hb_bytes   = (size_t)T_DIM * I_DIM * 2;           // 11.3 MB
    const size_t wdt_bytes  = (size_t)H_DIM * I_DIM * 2;           // 90.2 MB
    const size_t part_bytes = (size_t)KSPLIT * T_DIM * H_DIM * 4;  // 33.6 MB

    us16*  xb   = (us16*)d_ws;
    us16*  hb   = (us16*)((char*)d_ws + xb_bytes);
    us16*  wdt  = (us16*)((char*)d_ws + xb_bytes + hb_bytes);
    float* part = (float*)((char*)d_ws + xb_bytes + hb_bytes + wdt_bytes);

    cvt_x_kernel<<<(T_DIM * H_DIM) / (256 * 8), 256, 0, stream>>>(x, xb);
    gemm1_fused<<<(I_DIM / 64) * (T_DIM / 128), 256, 0, stream>>>(xb, wg, wu, sg, su, hb);
    trans_wd<<<(I_DIM / 256) * (H_DIM / 16), 256, 0, stream>>>(wd, sd, wdt);

    if (ws_size >= xb_bytes + hb_bytes + wdt_bytes + part_bytes) {
        gemm2_splitk<true><<<(T_DIM / 128) * (H_DIM / 128) * KSPLIT, 256, 0, stream>>>(hb, wdt, part);
        reduce4_kernel<<<(T_DIM * H_DIM) / (256 * 4), 256, 0, stream>>>(part, out);
    } else {
        (void)hipMemsetAsync(out, 0, (size_t)T_DIM * H_DIM * sizeof(float), stream);
        gemm2_splitk<false><<<(T_DIM / 128) * (H_DIM / 128) * KSPLIT, 256, 0, stream>>>(hb, wdt, out);
    }
}